// Round 1
// baseline (269.331 us; speedup 1.0000x reference)
//
#include <hip/hip_runtime.h>
#include <math.h>

typedef __attribute__((ext_vector_type(8))) short short8;
typedef __attribute__((ext_vector_type(4))) float f32x4;

#define NSP 4096
#define CIN 256
#define ICH 128

__device__ __forceinline__ unsigned short f2bf(float x){
  union { float f; unsigned u; } v; v.f = x;
  unsigned r = v.u + 0x7FFFu + ((v.u >> 16) & 1u);
  return (unsigned short)(r >> 16);
}
__device__ __forceinline__ float bf2f(unsigned short b){
  union { float f; unsigned u; } v; v.u = ((unsigned)b) << 16;
  return v.f;
}
// LDS anti-bank-conflict swizzle (element units; chunk-of-8 preserving)
__device__ __forceinline__ int swz(int row, int e){ return e ^ ((row & 7) << 3); }

__device__ __forceinline__ f32x4 mfma16(short8 a, short8 b, f32x4 c){
  return __builtin_amdgcn_mfma_f32_16x16x32_bf16(a, b, c, 0, 0, 0);
}

__device__ __forceinline__ void st4(unsigned short* p, unsigned short a, unsigned short b,
                                    unsigned short c, unsigned short d){
  ushort4 v; v.x=a; v.y=b; v.z=c; v.w=d;
  *(ushort4*)p = v;
}

// ---------------------------------------------------------------------------
// Branch conv: out[o,n] = act( (sum_c W[o,c] x[b,c,n] + bias)*scale + shift )
// ORIENT=1: writes out as [b][n][128] (for theta/phi, feeds attention Q/K)
// ORIENT=0: writes out as [b][128][n] (for g, feeds attention V)
// K=256 with split-bf16 (hi/lo, 3 products) for ~fp32 accuracy.
// ---------------------------------------------------------------------------
template<int ORIENT, int RELU>
__global__ __launch_bounds__(256) void conv_bn_k(
    const float* __restrict__ x, const float* __restrict__ Wm,
    const float* __restrict__ bias, const float* __restrict__ gamma,
    const float* __restrict__ beta, const float* __restrict__ mean,
    const float* __restrict__ var, float* __restrict__ out)
{
  const int b = blockIdx.z, nt = blockIdx.x, ot = blockIdx.y;
  const int n0 = nt*64, o0 = ot*64;
  const int t = threadIdx.x, w = t>>6, l = t&63;
  __shared__ unsigned short xs_h[64][64], xs_l[64][64];   // [n][c]
  __shared__ unsigned short ws_h[64][64], ws_l[64][64];   // [o][c]
  __shared__ float sc_s[64], sh_s[64];
  if (t < 64){
    int o = o0 + t;
    float s = gamma[o] * rsqrtf(var[o] + 1e-5f);
    sc_s[t] = s;
    sh_s[t] = beta[o] - mean[o]*s + bias[o]*s;
  }
  const f32x4 Z = {0.f,0.f,0.f,0.f};
  f32x4 acc[4];
  for (int i=0;i<4;++i) acc[i] = Z;

  for (int kc = 0; kc < CIN; kc += 64){
    __syncthreads();
    #pragma unroll
    for (int p = 0; p < 4; ++p){
      int cw = p*16 + (t>>4);
      int q4 = (t&15)*4;
      // x tile: global [c][n] -> LDS [n][c] (transpose, scalar writes)
      float4 xv = *(const float4*)(x + ((size_t)b*CIN + kc + cw)*NSP + n0 + q4);
      float xa[4] = {xv.x, xv.y, xv.z, xv.w};
      #pragma unroll
      for (int i=0;i<4;++i){
        int r = q4 + i;
        unsigned short h = f2bf(xa[i]);
        unsigned short lo = f2bf(xa[i] - bf2f(h));
        int cs = swz(r, cw);
        xs_h[r][cs] = h; xs_l[r][cs] = lo;
      }
      // W tile: global [o][c] -> LDS [o][c] (direct, vector writes)
      float4 wv = *(const float4*)(Wm + (size_t)(o0 + cw)*CIN + kc + q4);
      float wa[4] = {wv.x, wv.y, wv.z, wv.w};
      unsigned short wh[4], wlo[4];
      #pragma unroll
      for (int i=0;i<4;++i){
        wh[i] = f2bf(wa[i]);
        wlo[i] = f2bf(wa[i] - bf2f(wh[i]));
      }
      int cs = swz(cw, q4);
      st4(&ws_h[cw][cs], wh[0],wh[1],wh[2],wh[3]);
      st4(&ws_l[cw][cs], wlo[0],wlo[1],wlo[2],wlo[3]);
    }
    __syncthreads();
    #pragma unroll
    for (int kf = 0; kf < 2; ++kf){
      int ko = kf*32 + (l>>4)*8;
      int wr = 16*w + (l&15);
      short8 wh = *(const short8*)&ws_h[wr][swz(wr, ko)];
      short8 wl = *(const short8*)&ws_l[wr][swz(wr, ko)];
      #pragma unroll
      for (int nf = 0; nf < 4; ++nf){
        int xr = 16*nf + (l&15);
        short8 xh = *(const short8*)&xs_h[xr][swz(xr, ko)];
        short8 xl = *(const short8*)&xs_l[xr][swz(xr, ko)];
        if (ORIENT == 1){
          acc[nf] = mfma16(xh, wh, acc[nf]);
          acc[nf] = mfma16(xh, wl, acc[nf]);
          acc[nf] = mfma16(xl, wh, acc[nf]);
        } else {
          acc[nf] = mfma16(wh, xh, acc[nf]);
          acc[nf] = mfma16(wh, xl, acc[nf]);
          acc[nf] = mfma16(wl, xh, acc[nf]);
        }
      }
    }
  }
  if (ORIENT == 1){
    // D rows = n, cols = o. lane col o = 16w + (l&15)
    int ol = 16*w + (l&15);
    float s = sc_s[ol], sh = sh_s[ol];
    #pragma unroll
    for (int nf=0; nf<4; ++nf)
      #pragma unroll
      for (int j=0;j<4;++j){
        int n = n0 + 16*nf + (l>>4)*4 + j;
        float v = acc[nf][j]*s + sh;
        if (RELU) v = fmaxf(v, 0.f);
        out[((size_t)b*NSP + n)*ICH + o0 + ol] = v;
      }
  } else {
    // D rows = o, cols = n
    #pragma unroll
    for (int j=0;j<4;++j){
      int ol = 16*w + (l>>4)*4 + j;
      float s = sc_s[ol], sh = sh_s[ol];
      #pragma unroll
      for (int nf=0;nf<4;++nf){
        int n = n0 + 16*nf + (l&15);
        float v = acc[nf][j]*s + sh;
        if (RELU) v = fmaxf(v, 0.f);
        out[((size_t)b*ICH + o0 + ol)*NSP + n] = v;
      }
    }
  }
}

// ---------------------------------------------------------------------------
// Flash attention: Q=theta^T[n][c], K=phi^T[m][c], V=g[c][m].
// 64-row Q tile per block (4 waves x 16 rows), KV tiles of 64, online softmax.
// QK^T in split-bf16 (3 products), PV in plain bf16.
// ---------------------------------------------------------------------------
__global__ __launch_bounds__(256) void attn_k(
  const float* __restrict__ thp, const float* __restrict__ php,
  const float* __restrict__ gb, float* __restrict__ yt)
{
  const int b = blockIdx.y, qt = blockIdx.x;
  const int n0 = qt*64;
  const int t = threadIdx.x, w = t>>6, l = t&63;
  __shared__ unsigned short qh[64][128], ql[64][128];
  __shared__ unsigned short kh[64][128], kl[64][128];
  __shared__ unsigned short vs[128][64];
  __shared__ unsigned short ps[64][64];

  // stage Q tile (hi/lo split)
  #pragma unroll
  for (int p=0;p<8;++p){
    int r = p*8 + (t>>5);
    int c4 = (t&31)*4;
    float4 v = *(const float4*)(thp + ((size_t)b*NSP + n0 + r)*ICH + c4);
    float a[4]={v.x,v.y,v.z,v.w};
    unsigned short h[4], lo[4];
    #pragma unroll
    for (int i=0;i<4;++i){ h[i]=f2bf(a[i]); lo[i]=f2bf(a[i]-bf2f(h[i])); }
    int cs = swz(r, c4);
    st4(&qh[r][cs], h[0],h[1],h[2],h[3]);
    st4(&ql[r][cs], lo[0],lo[1],lo[2],lo[3]);
  }
  __syncthreads();
  short8 qfh[4], qfl[4];
  {
    int qr = 16*w + (l&15);
    #pragma unroll
    for (int kf=0;kf<4;++kf){
      int ko = kf*32 + (l>>4)*8;
      qfh[kf] = *(const short8*)&qh[qr][swz(qr,ko)];
      qfl[kf] = *(const short8*)&ql[qr][swz(qr,ko)];
    }
  }
  const f32x4 Z = {0.f,0.f,0.f,0.f};
  f32x4 oa[8];
  for (int i=0;i<8;++i) oa[i]=Z;
  float m_run[4] = {-1e30f,-1e30f,-1e30f,-1e30f};
  float l_run[4] = {0.f,0.f,0.f,0.f};

  for (int mt=0; mt<64; ++mt){
    int m0 = mt*64;
    __syncthreads();
    // stage K (phi^T tile, hi/lo)
    #pragma unroll
    for (int p=0;p<8;++p){
      int r = p*8 + (t>>5);
      int c4 = (t&31)*4;
      float4 v = *(const float4*)(php + ((size_t)b*NSP + m0 + r)*ICH + c4);
      float a[4]={v.x,v.y,v.z,v.w};
      unsigned short h[4], lo[4];
      #pragma unroll
      for (int i=0;i<4;++i){ h[i]=f2bf(a[i]); lo[i]=f2bf(a[i]-bf2f(h[i])); }
      int cs = swz(r, c4);
      st4(&kh[r][cs], h[0],h[1],h[2],h[3]);
      st4(&kl[r][cs], lo[0],lo[1],lo[2],lo[3]);
    }
    // stage V (g tile, plain bf16), layout [c][m]
    #pragma unroll
    for (int p=0;p<8;++p){
      int c = p*16 + (t>>4);
      int m4 = (t&15)*4;
      float4 v = *(const float4*)(gb + ((size_t)b*ICH + c)*NSP + m0 + m4);
      int cs = swz(c, m4);
      st4(&vs[c][cs], f2bf(v.x), f2bf(v.y), f2bf(v.z), f2bf(v.w));
    }
    __syncthreads();
    // QK^T: f tile 16(rows n) x 64(cols m) per wave
    f32x4 f[4];
    for (int i=0;i<4;++i) f[i]=Z;
    #pragma unroll
    for (int mf=0; mf<4; ++mf){
      int kr = 16*mf + (l&15);
      #pragma unroll
      for (int kf=0; kf<4; ++kf){
        int ko = kf*32 + (l>>4)*8;
        short8 bh = *(const short8*)&kh[kr][swz(kr,ko)];
        short8 bl = *(const short8*)&kl[kr][swz(kr,ko)];
        f[mf] = mfma16(qfh[kf], bh, f[mf]);
        f[mf] = mfma16(qfh[kf], bl, f[mf]);
        f[mf] = mfma16(qfl[kf], bh, f[mf]);
      }
    }
    // online softmax (rows owned per lane: row = (l>>4)*4 + j)
    float alpha[4];
    #pragma unroll
    for (int j=0;j<4;++j){
      float mx = fmaxf(fmaxf(f[0][j], f[1][j]), fmaxf(f[2][j], f[3][j]));
      mx = fmaxf(mx, __shfl_xor(mx, 1));
      mx = fmaxf(mx, __shfl_xor(mx, 2));
      mx = fmaxf(mx, __shfl_xor(mx, 4));
      mx = fmaxf(mx, __shfl_xor(mx, 8));
      float mn = fmaxf(m_run[j], mx);
      alpha[j] = __expf(m_run[j] - mn);
      m_run[j] = mn;
      float s = 0.f;
      #pragma unroll
      for (int mf=0;mf<4;++mf){
        float pv = __expf(f[mf][j] - mn);
        f[mf][j] = pv;
        s += pv;
      }
      s += __shfl_xor(s, 1);
      s += __shfl_xor(s, 2);
      s += __shfl_xor(s, 4);
      s += __shfl_xor(s, 8);
      l_run[j] = l_run[j]*alpha[j] + s;
    }
    #pragma unroll
    for (int cf=0;cf<8;++cf)
      #pragma unroll
      for (int j=0;j<4;++j)
        oa[cf][j] *= alpha[j];
    // write P (C/D layout -> [n][m] LDS, wave-private rows)
    #pragma unroll
    for (int mf=0;mf<4;++mf)
      #pragma unroll
      for (int j=0;j<4;++j){
        int r = 16*w + (l>>4)*4 + j;
        int cc = 16*mf + (l&15);
        ps[r][swz(r,cc)] = f2bf(f[mf][j]);
      }
    // PV: O[n][c] += P[n][m] * V[m][c]   (V[m][c] = g[c][m] = vs[c][m])
    int pr = 16*w + (l&15);
    #pragma unroll
    for (int mk=0;mk<2;++mk){
      int ko = mk*32 + (l>>4)*8;
      short8 ap = *(const short8*)&ps[pr][swz(pr,ko)];
      #pragma unroll
      for (int cf=0;cf<8;++cf){
        int vr = 16*cf + (l&15);
        short8 bv = *(const short8*)&vs[vr][swz(vr,ko)];
        oa[cf] = mfma16(ap, bv, oa[cf]);
      }
    }
  }
  // epilogue: normalize, write y^T [b][n][c]
  #pragma unroll
  for (int j=0;j<4;++j){
    float inv = 1.f / l_run[j];
    #pragma unroll
    for (int cf=0;cf<8;++cf){
      int n = n0 + 16*w + (l>>4)*4 + j;
      int c = 16*cf + (l&15);
      yt[((size_t)b*NSP + n)*ICH + c] = oa[cf][j]*inv;
    }
  }
}

// ---------------------------------------------------------------------------
// Final conv: out[b,o,n] = (sum_ic W2[o,ic] y[ic,n])*scale + shift' + x[b,o,n]
// y given as y^T [b][n][ic]. Plain bf16, K=128.
// ---------------------------------------------------------------------------
__global__ __launch_bounds__(256) void final_k(
  const float* __restrict__ yt, const float* __restrict__ x,
  const float* __restrict__ Wm, const float* __restrict__ bias,
  const float* __restrict__ gamma, const float* __restrict__ beta,
  const float* __restrict__ mean, const float* __restrict__ var,
  float* __restrict__ out)
{
  const int b = blockIdx.z, ot = blockIdx.y, nt = blockIdx.x;
  const int n0 = nt*64, o0 = ot*64;
  const int t = threadIdx.x, w = t>>6, l = t&63;
  __shared__ unsigned short ys[64][128];   // [n][ic]
  __shared__ unsigned short w2s[64][128];  // [o][ic]
  __shared__ float sc_s[64], sh_s[64];
  if (t < 64){
    int o = o0 + t;
    float s = gamma[o]*rsqrtf(var[o]+1e-5f);
    sc_s[t]=s; sh_s[t]=beta[o]-mean[o]*s+bias[o]*s;
  }
  #pragma unroll
  for (int p=0;p<8;++p){
    int r = p*8 + (t>>5);
    int c4 = (t&31)*4;
    float4 v = *(const float4*)(yt + ((size_t)b*NSP + n0 + r)*ICH + c4);
    int cs = swz(r, c4);
    st4(&ys[r][cs], f2bf(v.x), f2bf(v.y), f2bf(v.z), f2bf(v.w));
    float4 u = *(const float4*)(Wm + (size_t)(o0 + r)*ICH + c4);
    st4(&w2s[r][cs], f2bf(u.x), f2bf(u.y), f2bf(u.z), f2bf(u.w));
  }
  __syncthreads();
  const f32x4 Z = {0.f,0.f,0.f,0.f};
  f32x4 acc[4];
  for (int i=0;i<4;++i) acc[i]=Z;
  #pragma unroll
  for (int kf=0;kf<4;++kf){
    int ko = kf*32 + (l>>4)*8;
    int wr = 16*w + (l&15);
    short8 a = *(const short8*)&w2s[wr][swz(wr,ko)];
    #pragma unroll
    for (int nf=0;nf<4;++nf){
      int yr = 16*nf + (l&15);
      short8 bb = *(const short8*)&ys[yr][swz(yr,ko)];
      acc[nf] = mfma16(a, bb, acc[nf]);
    }
  }
  #pragma unroll
  for (int j=0;j<4;++j){
    int ol = 16*w + (l>>4)*4 + j;
    float s = sc_s[ol], sh = sh_s[ol];
    #pragma unroll
    for (int nf=0;nf<4;++nf){
      int n = n0 + 16*nf + (l&15);
      size_t idx = ((size_t)b*CIN + o0 + ol)*NSP + n;
      out[idx] = acc[nf][j]*s + sh + x[idx];
    }
  }
}

extern "C" void kernel_launch(void* const* d_in, const int* in_sizes, int n_in,
                              void* d_out, int out_size, void* d_ws, size_t ws_size,
                              hipStream_t stream){
  const float* x    = (const float*)d_in[0];
  const float* g_w  = (const float*)d_in[1];
  const float* g_b  = (const float*)d_in[2];
  const float* g_ga = (const float*)d_in[3];
  const float* g_be = (const float*)d_in[4];
  const float* g_me = (const float*)d_in[5];
  const float* g_va = (const float*)d_in[6];
  const float* t_w  = (const float*)d_in[7];
  const float* t_b  = (const float*)d_in[8];
  const float* t_ga = (const float*)d_in[9];
  const float* t_be = (const float*)d_in[10];
  const float* t_me = (const float*)d_in[11];
  const float* t_va = (const float*)d_in[12];
  const float* p_w  = (const float*)d_in[13];
  const float* p_b  = (const float*)d_in[14];
  const float* p_ga = (const float*)d_in[15];
  const float* p_be = (const float*)d_in[16];
  const float* p_me = (const float*)d_in[17];
  const float* p_va = (const float*)d_in[18];
  const float* w_w  = (const float*)d_in[19];
  const float* w_b  = (const float*)d_in[20];
  const float* w_ga = (const float*)d_in[21];
  const float* w_be = (const float*)d_in[22];
  const float* w_me = (const float*)d_in[23];
  const float* w_va = (const float*)d_in[24];

  float* ws = (float*)d_ws;
  const size_t SEG = (size_t)4*NSP*ICH;   // 2,097,152 floats = 8 MB
  float* th_t = ws;            // theta^T [b][n][c]
  float* ph_t = ws + SEG;      // phi^T   [b][n][c]
  float* g_cn = ws + 2*SEG;    // g       [b][c][n]
  float* y_t  = ws + 3*SEG;    // y^T     [b][n][c]

  dim3 blk(256,1,1);
  conv_bn_k<1,1><<<dim3(64,2,4), blk, 0, stream>>>(x, t_w, t_b, t_ga, t_be, t_me, t_va, th_t);
  conv_bn_k<1,1><<<dim3(64,2,4), blk, 0, stream>>>(x, p_w, p_b, p_ga, p_be, p_me, p_va, ph_t);
  conv_bn_k<0,1><<<dim3(64,2,4), blk, 0, stream>>>(x, g_w, g_b, g_ga, g_be, g_me, g_va, g_cn);
  attn_k<<<dim3(64,4,1), blk, 0, stream>>>(th_t, ph_t, g_cn, y_t);
  final_k<<<dim3(64,4,4), blk, 0, stream>>>(y_t, x, w_w, w_b, w_ga, w_be, w_me, w_va, (float*)d_out);
}

// Round 2
// 155.964 us; speedup vs baseline: 1.7269x; 1.7269x over previous
//
#include <hip/hip_runtime.h>
#include <math.h>

typedef __attribute__((ext_vector_type(8))) short short8;
typedef __attribute__((ext_vector_type(8))) _Float16 half8;
typedef __attribute__((ext_vector_type(4))) float f32x4;

#define NSP 4096
#define CIN 256
#define ICH 128
#define SPLITS 4
#define TILES_PER_SPLIT 16

__device__ __forceinline__ unsigned short f2h(float x){
  union { _Float16 h; unsigned short u; } v; v.h = (_Float16)x; return v.u;
}
__device__ __forceinline__ float h2f(unsigned short u){
  union { _Float16 h; unsigned short u; } v; v.u = u; return (float)v.h;
}
// LDS anti-bank-conflict swizzle (element units; chunk-of-8 preserving)
__device__ __forceinline__ int swz(int row, int e){ return e ^ ((row & 7) << 3); }

__device__ __forceinline__ f32x4 mfmah(short8 a, short8 b, f32x4 c){
  union { short8 s; half8 h; } ua, ub; ua.s = a; ub.s = b;
  return __builtin_amdgcn_mfma_f32_16x16x32_f16(ua.h, ub.h, c, 0, 0, 0);
}

__device__ __forceinline__ void st4h(unsigned short* p, unsigned short a, unsigned short b,
                                     unsigned short c, unsigned short d){
  ushort4 v; v.x=a; v.y=b; v.z=c; v.w=d;
  *(ushort4*)p = v;
}

// ---------------------------------------------------------------------------
// Branch conv: out[o,n] = relu( (sum_c W[o,c] x[b,c,n])*scale + shift )
// ORIENT=1: writes fp16 out as [b][n][128] (theta/phi -> attention Q/K)
// ORIENT=0: writes fp16 out as [b][128][n] (g -> attention V)
// ---------------------------------------------------------------------------
template<int ORIENT>
__global__ __launch_bounds__(256) void conv_bn_k(
    const float* __restrict__ x, const float* __restrict__ Wm,
    const float* __restrict__ bias, const float* __restrict__ gamma,
    const float* __restrict__ beta, const float* __restrict__ mean,
    const float* __restrict__ var, unsigned short* __restrict__ out)
{
  const int b = blockIdx.z, nt = blockIdx.x, ot = blockIdx.y;
  const int n0 = nt*64, o0 = ot*64;
  const int t = threadIdx.x, w = t>>6, l = t&63;
  __shared__ unsigned short xs[64][64];   // [n][c]  fp16
  __shared__ unsigned short ws[64][64];   // [o][c]  fp16
  __shared__ float sc_s[64], sh_s[64];
  if (t < 64){
    int o = o0 + t;
    float s = gamma[o] * rsqrtf(var[o] + 1e-5f);
    sc_s[t] = s;
    sh_s[t] = beta[o] - mean[o]*s + bias[o]*s;
  }
  const f32x4 Z = {0.f,0.f,0.f,0.f};
  f32x4 acc[4];
  for (int i=0;i<4;++i) acc[i] = Z;

  for (int kc = 0; kc < CIN; kc += 64){
    __syncthreads();
    #pragma unroll
    for (int p = 0; p < 4; ++p){
      int cw = p*16 + (t>>4);
      int q4 = (t&15)*4;
      // x tile: global [c][n] -> LDS [n][c] (transpose, scalar fp16 writes)
      float4 xv = *(const float4*)(x + ((size_t)b*CIN + kc + cw)*NSP + n0 + q4);
      float xa[4] = {xv.x, xv.y, xv.z, xv.w};
      #pragma unroll
      for (int i=0;i<4;++i){
        int r = q4 + i;
        xs[r][swz(r, cw)] = f2h(xa[i]);
      }
      // W tile: global [o][c] -> LDS [o][c]
      float4 wv = *(const float4*)(Wm + (size_t)(o0 + cw)*CIN + kc + q4);
      int cs = swz(cw, q4);
      st4h(&ws[cw][cs], f2h(wv.x), f2h(wv.y), f2h(wv.z), f2h(wv.w));
    }
    __syncthreads();
    #pragma unroll
    for (int kf = 0; kf < 2; ++kf){
      int ko = kf*32 + (l>>4)*8;
      int wr = 16*w + (l&15);
      short8 wf = *(const short8*)&ws[wr][swz(wr, ko)];
      #pragma unroll
      for (int nf = 0; nf < 4; ++nf){
        int xr = 16*nf + (l&15);
        short8 xf = *(const short8*)&xs[xr][swz(xr, ko)];
        if (ORIENT == 1) acc[nf] = mfmah(xf, wf, acc[nf]);
        else             acc[nf] = mfmah(wf, xf, acc[nf]);
      }
    }
  }
  if (ORIENT == 1){
    // D rows = n, cols = o
    int ol = 16*w + (l&15);
    float s = sc_s[ol], sh = sh_s[ol];
    #pragma unroll
    for (int nf=0; nf<4; ++nf)
      #pragma unroll
      for (int j=0;j<4;++j){
        int n = n0 + 16*nf + (l>>4)*4 + j;
        float v = fmaxf(acc[nf][j]*s + sh, 0.f);
        out[((size_t)b*NSP + n)*ICH + o0 + ol] = f2h(v);
      }
  } else {
    // D rows = o, cols = n
    #pragma unroll
    for (int j=0;j<4;++j){
      int ol = 16*w + (l>>4)*4 + j;
      float s = sc_s[ol], sh = sh_s[ol];
      #pragma unroll
      for (int nf=0;nf<4;++nf){
        int n = n0 + 16*nf + (l&15);
        float v = fmaxf(acc[nf][j]*s + sh, 0.f);
        out[((size_t)b*ICH + o0 + ol)*NSP + n] = f2h(v);
      }
    }
  }
}

// ---------------------------------------------------------------------------
// Flash attention with KV-split: block (qt,b,s) processes Q rows [64*qt,+64)
// against KV tiles [16s, 16s+16). Writes normalized partial yhat (fp16) and
// per-row (m,l) for the combine. fp16 MFMA throughout, fp32 softmax.
// ---------------------------------------------------------------------------
__global__ __launch_bounds__(256, 4) void attn_k(
  const unsigned short* __restrict__ thp, const unsigned short* __restrict__ php,
  const unsigned short* __restrict__ gb, unsigned short* __restrict__ ypart,
  float* __restrict__ ml)
{
  const int qt = blockIdx.x, b = blockIdx.y, s = blockIdx.z;
  const int n0 = qt*64;
  const int t = threadIdx.x, w = t>>6, l = t&63;
  __shared__ unsigned short ks[64][128];   // K (or Q staging)  fp16
  __shared__ unsigned short vs[128][64];   // V ([c][m])        fp16
  __shared__ unsigned short ps[64][64];    // P                 fp16

  // stage Q tile through ks, pull fragments to registers
  #pragma unroll
  for (int p=0;p<4;++p){
    int id = p*256 + t, r = id>>4, c8 = (id&15)*8;
    *(short8*)&ks[r][swz(r,c8)] =
        *(const short8*)(thp + ((size_t)b*NSP + n0 + r)*ICH + c8);
  }
  __syncthreads();
  short8 qf[4];
  {
    int qr = 16*w + (l&15);
    #pragma unroll
    for (int kf=0;kf<4;++kf)
      qf[kf] = *(const short8*)&ks[qr][swz(qr, kf*32 + (l>>4)*8)];
  }
  const f32x4 Z = {0.f,0.f,0.f,0.f};
  f32x4 oa[8];
  for (int i=0;i<8;++i) oa[i]=Z;
  float m_run[4] = {-1e30f,-1e30f,-1e30f,-1e30f};
  float l_run[4] = {0.f,0.f,0.f,0.f};

  for (int mt = s*TILES_PER_SPLIT; mt < (s+1)*TILES_PER_SPLIT; ++mt){
    int m0 = mt*64;
    __syncthreads();
    // stage K tile (phi^T rows)
    #pragma unroll
    for (int p=0;p<4;++p){
      int id = p*256 + t, r = id>>4, c8 = (id&15)*8;
      *(short8*)&ks[r][swz(r,c8)] =
          *(const short8*)(php + ((size_t)b*NSP + m0 + r)*ICH + c8);
    }
    // stage V tile (g rows [c][m])
    #pragma unroll
    for (int p=0;p<4;++p){
      int id = p*256 + t, c = id>>3, m8 = (id&7)*8;
      *(short8*)&vs[c][swz(c,m8)] =
          *(const short8*)(gb + ((size_t)b*ICH + c)*NSP + m0 + m8);
    }
    __syncthreads();
    // QK^T: f tile 16(rows n) x 64(cols m) per wave
    f32x4 f[4];
    for (int i=0;i<4;++i) f[i]=Z;
    #pragma unroll
    for (int mf=0; mf<4; ++mf){
      int kr = 16*mf + (l&15);
      #pragma unroll
      for (int kf=0; kf<4; ++kf){
        short8 bh = *(const short8*)&ks[kr][swz(kr, kf*32 + (l>>4)*8)];
        f[mf] = mfmah(qf[kf], bh, f[mf]);
      }
    }
    // online softmax (rows owned per lane: row = (l>>4)*4 + j)
    float alpha[4];
    #pragma unroll
    for (int j=0;j<4;++j){
      float mx = fmaxf(fmaxf(f[0][j], f[1][j]), fmaxf(f[2][j], f[3][j]));
      mx = fmaxf(mx, __shfl_xor(mx, 1));
      mx = fmaxf(mx, __shfl_xor(mx, 2));
      mx = fmaxf(mx, __shfl_xor(mx, 4));
      mx = fmaxf(mx, __shfl_xor(mx, 8));
      float mn = fmaxf(m_run[j], mx);
      alpha[j] = __expf(m_run[j] - mn);
      m_run[j] = mn;
      float sm = 0.f;
      #pragma unroll
      for (int mf=0;mf<4;++mf){
        float pv = __expf(f[mf][j] - mn);
        f[mf][j] = pv;
        sm += pv;
      }
      sm += __shfl_xor(sm, 1);
      sm += __shfl_xor(sm, 2);
      sm += __shfl_xor(sm, 4);
      sm += __shfl_xor(sm, 8);
      l_run[j] = l_run[j]*alpha[j] + sm;
    }
    #pragma unroll
    for (int cf=0;cf<8;++cf)
      #pragma unroll
      for (int j=0;j<4;++j)
        oa[cf][j] *= alpha[j];
    // write P ([n][m] LDS, wave-private rows)
    #pragma unroll
    for (int mf=0;mf<4;++mf)
      #pragma unroll
      for (int j=0;j<4;++j){
        int r = 16*w + (l>>4)*4 + j;
        int cc = 16*mf + (l&15);
        ps[r][swz(r,cc)] = f2h(f[mf][j]);
      }
    // PV: O[n][c] += P[n][m] * V[m][c]  (vs[c][m])
    int pr = 16*w + (l&15);
    #pragma unroll
    for (int mk=0;mk<2;++mk){
      int ko = mk*32 + (l>>4)*8;
      short8 ap = *(const short8*)&ps[pr][swz(pr,ko)];
      #pragma unroll
      for (int cf=0;cf<8;++cf){
        int vr = 16*cf + (l&15);
        short8 bv = *(const short8*)&vs[vr][swz(vr,ko)];
        oa[cf] = mfmah(ap, bv, oa[cf]);
      }
    }
  }
  // epilogue: normalized partial yhat + (m,l)
  #pragma unroll
  for (int j=0;j<4;++j){
    float inv = 1.f / l_run[j];
    int n = n0 + 16*w + (l>>4)*4 + j;
    #pragma unroll
    for (int cf=0;cf<8;++cf){
      int c = 16*cf + (l&15);
      ypart[(((size_t)s*4 + b)*NSP + n)*ICH + c] = f2h(oa[cf][j]*inv);
    }
    if ((l&15)==0){
      ml[(((size_t)s*4 + b)*NSP + n)*2 + 0] = m_run[j];
      ml[(((size_t)s*4 + b)*NSP + n)*2 + 1] = l_run[j];
    }
  }
}

// ---------------------------------------------------------------------------
// Final conv + fused split-combine:
// y[n][c] = sum_s w_s[n] * yhat_s[n][c],  w_s = l_s e^{m_s-M} / L
// out[b,o,n] = (sum_ic W2[o,ic] y[n][ic])*scale + shift + x[b,o,n]
// ---------------------------------------------------------------------------
__global__ __launch_bounds__(256) void final_k(
  const unsigned short* __restrict__ ypart, const float* __restrict__ ml,
  const float* __restrict__ x, const float* __restrict__ Wm,
  const float* __restrict__ bias, const float* __restrict__ gamma,
  const float* __restrict__ beta, const float* __restrict__ mean,
  const float* __restrict__ var, float* __restrict__ out)
{
  const int b = blockIdx.z, ot = blockIdx.y, nt = blockIdx.x;
  const int n0 = nt*64, o0 = ot*64;
  const int t = threadIdx.x, w = t>>6, l = t&63;
  __shared__ unsigned short ys[64][128];   // combined y [n][ic] fp16
  __shared__ unsigned short w2s[64][128];  // [o][ic] fp16
  __shared__ float wc[SPLITS][64];         // combine weights
  __shared__ float sc_s[64], sh_s[64];
  if (t < 64){
    int o = o0 + t;
    float s = gamma[o]*rsqrtf(var[o]+1e-5f);
    sc_s[t]=s; sh_s[t]=beta[o]-mean[o]*s+bias[o]*s;
  } else if (t < 128){
    int r = t - 64, n = n0 + r;
    float mv[SPLITS], lv[SPLITS];
    #pragma unroll
    for (int s=0;s<SPLITS;++s){
      mv[s] = ml[(((size_t)s*4 + b)*NSP + n)*2 + 0];
      lv[s] = ml[(((size_t)s*4 + b)*NSP + n)*2 + 1];
    }
    float M = fmaxf(fmaxf(mv[0],mv[1]), fmaxf(mv[2],mv[3]));
    float wsum = 0.f, wv[SPLITS];
    #pragma unroll
    for (int s=0;s<SPLITS;++s){ wv[s] = lv[s]*__expf(mv[s]-M); wsum += wv[s]; }
    float inv = 1.f/wsum;
    #pragma unroll
    for (int s=0;s<SPLITS;++s) wc[s][r] = wv[s]*inv;
  }
  __syncthreads();
  // stage combined y and W2
  #pragma unroll
  for (int p=0;p<4;++p){
    int id = p*256 + t, r = id>>4, c8 = (id&15)*8;
    float accv[8] = {0,0,0,0,0,0,0,0};
    #pragma unroll
    for (int s=0;s<SPLITS;++s){
      short8 v = *(const short8*)(ypart + (((size_t)s*4 + b)*NSP + n0 + r)*ICH + c8);
      float wgt = wc[s][r];
      #pragma unroll
      for (int i=0;i<8;++i) accv[i] += wgt * h2f(((unsigned short*)&v)[i]);
    }
    unsigned short hv[8];
    #pragma unroll
    for (int i=0;i<8;++i) hv[i] = f2h(accv[i]);
    *(short8*)&ys[r][swz(r,c8)] = *(short8*)hv;

    float4 u0 = *(const float4*)(Wm + (size_t)(o0 + r)*ICH + c8);
    float4 u1 = *(const float4*)(Wm + (size_t)(o0 + r)*ICH + c8 + 4);
    unsigned short wh[8] = {f2h(u0.x),f2h(u0.y),f2h(u0.z),f2h(u0.w),
                            f2h(u1.x),f2h(u1.y),f2h(u1.z),f2h(u1.w)};
    *(short8*)&w2s[r][swz(r,c8)] = *(short8*)wh;
  }
  __syncthreads();
  const f32x4 Z = {0.f,0.f,0.f,0.f};
  f32x4 acc[4];
  for (int i=0;i<4;++i) acc[i]=Z;
  #pragma unroll
  for (int kf=0;kf<4;++kf){
    int ko = kf*32 + (l>>4)*8;
    int wr = 16*w + (l&15);
    short8 a = *(const short8*)&w2s[wr][swz(wr,ko)];
    #pragma unroll
    for (int nf=0;nf<4;++nf){
      int yr = 16*nf + (l&15);
      short8 bb = *(const short8*)&ys[yr][swz(yr,ko)];
      acc[nf] = mfmah(a, bb, acc[nf]);
    }
  }
  #pragma unroll
  for (int j=0;j<4;++j){
    int ol = 16*w + (l>>4)*4 + j;
    float s = sc_s[ol], sh = sh_s[ol];
    #pragma unroll
    for (int nf=0;nf<4;++nf){
      int n = n0 + 16*nf + (l&15);
      size_t idx = ((size_t)b*CIN + o0 + ol)*NSP + n;
      out[idx] = acc[nf][j]*s + sh + x[idx];
    }
  }
}

extern "C" void kernel_launch(void* const* d_in, const int* in_sizes, int n_in,
                              void* d_out, int out_size, void* d_ws, size_t ws_size,
                              hipStream_t stream){
  const float* x    = (const float*)d_in[0];
  const float* g_w  = (const float*)d_in[1];
  const float* g_b  = (const float*)d_in[2];
  const float* g_ga = (const float*)d_in[3];
  const float* g_be = (const float*)d_in[4];
  const float* g_me = (const float*)d_in[5];
  const float* g_va = (const float*)d_in[6];
  const float* t_w  = (const float*)d_in[7];
  const float* t_b  = (const float*)d_in[8];
  const float* t_ga = (const float*)d_in[9];
  const float* t_be = (const float*)d_in[10];
  const float* t_me = (const float*)d_in[11];
  const float* t_va = (const float*)d_in[12];
  const float* p_w  = (const float*)d_in[13];
  const float* p_b  = (const float*)d_in[14];
  const float* p_ga = (const float*)d_in[15];
  const float* p_be = (const float*)d_in[16];
  const float* p_me = (const float*)d_in[17];
  const float* p_va = (const float*)d_in[18];
  const float* w_w  = (const float*)d_in[19];
  const float* w_b  = (const float*)d_in[20];
  const float* w_ga = (const float*)d_in[21];
  const float* w_be = (const float*)d_in[22];
  const float* w_me = (const float*)d_in[23];
  const float* w_va = (const float*)d_in[24];

  char* ws = (char*)d_ws;
  const size_t SEG = (size_t)4*NSP*ICH*sizeof(unsigned short);   // 4 MB
  unsigned short* th_t  = (unsigned short*)(ws);                 // theta^T [b][n][c] fp16
  unsigned short* ph_t  = (unsigned short*)(ws + SEG);           // phi^T   [b][n][c] fp16
  unsigned short* g_cn  = (unsigned short*)(ws + 2*SEG);         // g       [b][c][n] fp16
  unsigned short* ypart = (unsigned short*)(ws + 3*SEG);         // yhat_s  [s][b][n][c] fp16 (16 MB)
  float*          mlb   = (float*)(ws + 3*SEG + SPLITS*SEG);     // (m,l)   [s][b][n][2] fp32

  dim3 blk(256,1,1);
  conv_bn_k<1><<<dim3(64,2,4), blk, 0, stream>>>(x, t_w, t_b, t_ga, t_be, t_me, t_va, th_t);
  conv_bn_k<1><<<dim3(64,2,4), blk, 0, stream>>>(x, p_w, p_b, p_ga, p_be, p_me, p_va, ph_t);
  conv_bn_k<0><<<dim3(64,2,4), blk, 0, stream>>>(x, g_w, g_b, g_ga, g_be, g_me, g_va, g_cn);
  attn_k<<<dim3(64,4,SPLITS), blk, 0, stream>>>(th_t, ph_t, g_cn, ypart, mlb);
  final_k<<<dim3(64,4,4), blk, 0, stream>>>(ypart, mlb, x, w_w, w_b, w_ga, w_be, w_me, w_va, (float*)d_out);
}

// Round 3
// 95.005 us; speedup vs baseline: 2.8349x; 1.6416x over previous
//
#include <hip/hip_runtime.h>
#include <math.h>

typedef __attribute__((ext_vector_type(8))) short short8;
typedef __attribute__((ext_vector_type(8))) _Float16 half8;
typedef __attribute__((ext_vector_type(4))) float f32x4;

#define NSP 4096
#define CIN 256
#define ICH 128
#define SPLITS 4
#define TILES_PER_SPLIT 16

__device__ __forceinline__ unsigned short f2h(float x){
  union { _Float16 h; unsigned short u; } v; v.h = (_Float16)x; return v.u;
}
__device__ __forceinline__ float h2f(unsigned short u){
  union { _Float16 h; unsigned short u; } v; v.u = u; return (float)v.h;
}
// LDS anti-bank-conflict swizzle (element units; 8-chunk preserving)
__device__ __forceinline__ int swz(int row, int e){ return e ^ ((row & 7) << 3); }

__device__ __forceinline__ f32x4 mfmah(short8 a, short8 b, f32x4 c){
  union { short8 s; half8 h; } ua, ub; ua.s = a; ub.s = b;
  return __builtin_amdgcn_mfma_f32_16x16x32_f16(ua.h, ub.h, c, 0, 0, 0);
}

__device__ __forceinline__ void st4h(unsigned short* p, unsigned short a, unsigned short b,
                                     unsigned short c, unsigned short d){
  ushort4 v; v.x=a; v.y=b; v.z=c; v.w=d;
  *(ushort4*)p = v;
}

// async global->LDS, 16B per lane. LDS dest = wave-uniform base + lane*16 (linear).
__device__ __forceinline__ void gload_lds16(const unsigned short* g, unsigned short* l){
  __builtin_amdgcn_global_load_lds(
      (const __attribute__((address_space(1))) unsigned int*)g,
      (__attribute__((address_space(3))) unsigned int*)l, 16, 0, 0);
}

// Stage a 64x128 fp16 tile (row stride 128 elems in global) into LDS flat [64][128]
// with read-side XOR swizzle pre-applied on the SOURCE address (rule 21).
__device__ __forceinline__ void stage_nc(const unsigned short* gbase, unsigned short* lds,
                                         int w, int l){
  #pragma unroll
  for (int i=0;i<4;++i){
    int rl = 16*w + 4*i + (l>>4);
    int eg = ((l&15)*8) ^ ((rl&7)<<3);
    gload_lds16(gbase + (size_t)rl*128 + eg, lds + w*2048 + i*512);
  }
}
// Stage a 128x64 fp16 tile (row stride NSP elems in global) into LDS flat [128][64].
__device__ __forceinline__ void stage_cn(const unsigned short* gbase, unsigned short* lds,
                                         int w, int l){
  #pragma unroll
  for (int i=0;i<4;++i){
    int cl = 32*w + 8*i + (l>>3);
    int me = ((l&7)*8) ^ ((cl&7)<<3);
    gload_lds16(gbase + (size_t)cl*NSP + me, lds + w*2048 + i*512);
  }
}

// ---------------------------------------------------------------------------
// Fused 3-branch conv+BN+ReLU: reads x once, computes g/theta/phi tiles.
// br0 = g  -> out [b][128][n] fp16 (orient0)
// br1 = th -> out [b][n][128] fp16 (orient1)
// br2 = ph -> out [b][n][128] fp16 (orient1)
// ---------------------------------------------------------------------------
__global__ __launch_bounds__(256) void conv_fused_k(
    const float* __restrict__ x,
    const float* __restrict__ w0, const float* __restrict__ b0,
    const float* __restrict__ ga0, const float* __restrict__ be0,
    const float* __restrict__ me0, const float* __restrict__ va0,
    const float* __restrict__ w1, const float* __restrict__ b1,
    const float* __restrict__ ga1, const float* __restrict__ be1,
    const float* __restrict__ me1, const float* __restrict__ va1,
    const float* __restrict__ w2, const float* __restrict__ b2,
    const float* __restrict__ ga2, const float* __restrict__ be2,
    const float* __restrict__ me2, const float* __restrict__ va2,
    unsigned short* __restrict__ outg, unsigned short* __restrict__ outt,
    unsigned short* __restrict__ outp)
{
  const int b = blockIdx.z, nt = blockIdx.x, ot = blockIdx.y;
  const int n0 = nt*64, o0 = ot*64;
  const int t = threadIdx.x, w = t>>6, l = t&63;
  __shared__ unsigned short xs[64][64];       // [n][c] fp16
  __shared__ unsigned short ws[3][64][64];    // [br][o][c] fp16
  __shared__ float sc_s[3][64], sh_s[3][64];
  if (t < 64){
    int o = o0 + t;
    float s0 = ga0[o]*rsqrtf(va0[o]+1e-5f);
    sc_s[0][t]=s0; sh_s[0][t]=be0[o]-me0[o]*s0+b0[o]*s0;
    float s1 = ga1[o]*rsqrtf(va1[o]+1e-5f);
    sc_s[1][t]=s1; sh_s[1][t]=be1[o]-me1[o]*s1+b1[o]*s1;
    float s2 = ga2[o]*rsqrtf(va2[o]+1e-5f);
    sc_s[2][t]=s2; sh_s[2][t]=be2[o]-me2[o]*s2+b2[o]*s2;
  }
  const f32x4 Z = {0.f,0.f,0.f,0.f};
  f32x4 acc[3][4];
  #pragma unroll
  for (int br=0;br<3;++br) for (int i=0;i<4;++i) acc[br][i] = Z;
  const float* Wt[3] = {w0, w1, w2};

  for (int kc = 0; kc < CIN; kc += 64){
    __syncthreads();
    #pragma unroll
    for (int p = 0; p < 4; ++p){
      int cw = p*16 + (t>>4);
      int q4 = (t&15)*4;
      // x tile: global [c][n] -> LDS [n][c] (transpose, scalar fp16 writes)
      float4 xv = *(const float4*)(x + ((size_t)b*CIN + kc + cw)*NSP + n0 + q4);
      float xa[4] = {xv.x, xv.y, xv.z, xv.w};
      #pragma unroll
      for (int i=0;i<4;++i){
        int r = q4 + i;
        xs[r][swz(r, cw)] = f2h(xa[i]);
      }
      // 3 W tiles: global [o][c] -> LDS [o][c]
      #pragma unroll
      for (int br=0;br<3;++br){
        float4 wv = *(const float4*)(Wt[br] + (size_t)(o0 + cw)*CIN + kc + q4);
        int cs = swz(cw, q4);
        st4h(&ws[br][cw][cs], f2h(wv.x), f2h(wv.y), f2h(wv.z), f2h(wv.w));
      }
    }
    __syncthreads();
    #pragma unroll
    for (int kf = 0; kf < 2; ++kf){
      int ko = kf*32 + (l>>4)*8;
      int wr = 16*w + (l&15);
      short8 wf0 = *(const short8*)&ws[0][wr][swz(wr, ko)];
      short8 wf1 = *(const short8*)&ws[1][wr][swz(wr, ko)];
      short8 wf2 = *(const short8*)&ws[2][wr][swz(wr, ko)];
      #pragma unroll
      for (int nf = 0; nf < 4; ++nf){
        int xr = 16*nf + (l&15);
        short8 xf = *(const short8*)&xs[xr][swz(xr, ko)];
        acc[0][nf] = mfmah(wf0, xf, acc[0][nf]);   // orient0 (g)
        acc[1][nf] = mfmah(xf, wf1, acc[1][nf]);   // orient1 (theta)
        acc[2][nf] = mfmah(xf, wf2, acc[2][nf]);   // orient1 (phi)
      }
    }
  }
  // epilogue g (orient0): D rows = o, cols = n
  #pragma unroll
  for (int j=0;j<4;++j){
    int ol = 16*w + (l>>4)*4 + j;
    float s = sc_s[0][ol], sh = sh_s[0][ol];
    #pragma unroll
    for (int nf=0;nf<4;++nf){
      int n = n0 + 16*nf + (l&15);
      float v = fmaxf(acc[0][nf][j]*s + sh, 0.f);
      outg[((size_t)b*ICH + o0 + ol)*NSP + n] = f2h(v);
    }
  }
  // epilogue theta/phi (orient1): D rows = n, cols = o
  {
    int ol = 16*w + (l&15);
    float s1 = sc_s[1][ol], sh1 = sh_s[1][ol];
    float s2 = sc_s[2][ol], sh2 = sh_s[2][ol];
    #pragma unroll
    for (int nf=0; nf<4; ++nf)
      #pragma unroll
      for (int j=0;j<4;++j){
        int n = n0 + 16*nf + (l>>4)*4 + j;
        float v1 = fmaxf(acc[1][nf][j]*s1 + sh1, 0.f);
        float v2 = fmaxf(acc[2][nf][j]*s2 + sh2, 0.f);
        outt[((size_t)b*NSP + n)*ICH + o0 + ol] = f2h(v1);
        outp[((size_t)b*NSP + n)*ICH + o0 + ol] = f2h(v2);
      }
  }
}

// ---------------------------------------------------------------------------
// Flash attention, Q=128 rows/block, double-buffered K/V via global_load_lds,
// 2-phase pipeline (prefetch -> compute -> barrier), KV-split over 4 splits.
// ---------------------------------------------------------------------------
__global__ __launch_bounds__(256, 2) void attn_k(
  const unsigned short* __restrict__ thp, const unsigned short* __restrict__ php,
  const unsigned short* __restrict__ gb, unsigned short* __restrict__ ypart,
  float* __restrict__ ml)
{
  // bijective XCD-aware decode: each XCD gets 2 (b,s) combos x 32 qt blocks
  const int bx = blockIdx.x;
  const int xcd = bx & 7, jj = bx >> 3;
  const int combo = xcd*2 + (jj>>5);
  const int qt = jj & 31;
  const int b = combo & 3, s = combo >> 2;
  const int n0 = qt*128;
  const int t = threadIdx.x, w = t>>6, l = t&63;

  __shared__ unsigned short kb[2][64][128];   // K double buffer
  __shared__ unsigned short vb[2][128][64];   // V double buffer ([c][m])
  __shared__ unsigned short ps[128][64];      // P tile

  // ---- stage Q (both halves) through kb, pull fragments ----
  stage_nc(thp + ((size_t)b*NSP + n0      )*ICH, &kb[0][0][0], w, l);
  stage_nc(thp + ((size_t)b*NSP + n0 + 64 )*ICH, &kb[1][0][0], w, l);
  __syncthreads();
  short8 qf0[4], qf1[4];
  {
    int qr = 16*w + (l&15);
    #pragma unroll
    for (int kf=0;kf<4;++kf){
      int ko = kf*32 + (l>>4)*8;
      qf0[kf] = *(const short8*)&kb[0][qr][swz(qr, ko)];
      qf1[kf] = *(const short8*)&kb[1][qr][swz(qr, ko)];
    }
  }
  __syncthreads();   // all waves done reading Q before restage

  const f32x4 Z = {0.f,0.f,0.f,0.f};
  f32x4 oa0[8], oa1[8];
  #pragma unroll
  for (int i=0;i<8;++i){ oa0[i]=Z; oa1[i]=Z; }
  float m0r[4] = {-1e30f,-1e30f,-1e30f,-1e30f};
  float m1r[4] = {-1e30f,-1e30f,-1e30f,-1e30f};
  float l0r[4] = {0.f,0.f,0.f,0.f};
  float l1r[4] = {0.f,0.f,0.f,0.f};

  const int tile0 = s*TILES_PER_SPLIT;
  // prologue stage tile0 -> buf0
  stage_nc(php + ((size_t)b*NSP + tile0*64)*ICH, &kb[0][0][0], w, l);
  stage_cn(gb + (size_t)b*ICH*NSP + tile0*64,    &vb[0][0][0], w, l);
  __syncthreads();
  int cur = 0;

  for (int it = 0; it < TILES_PER_SPLIT; ++it){
    // prefetch next tile into other buffer (latency hidden under compute)
    if (it < TILES_PER_SPLIT-1){
      int m0n = (tile0 + it + 1)*64;
      stage_nc(php + ((size_t)b*NSP + m0n)*ICH, &kb[cur^1][0][0], w, l);
      stage_cn(gb + (size_t)b*ICH*NSP + m0n,    &vb[cur^1][0][0], w, l);
    }
    // ---- QK^T, K fragments shared across halves ----
    f32x4 f0[4], f1[4];
    #pragma unroll
    for (int i=0;i<4;++i){ f0[i]=Z; f1[i]=Z; }
    __builtin_amdgcn_s_setprio(1);
    #pragma unroll
    for (int mf=0; mf<4; ++mf){
      int kr = 16*mf + (l&15);
      #pragma unroll
      for (int kf=0; kf<4; ++kf){
        short8 bh = *(const short8*)&kb[cur][kr][swz(kr, kf*32 + (l>>4)*8)];
        f0[mf] = mfmah(qf0[kf], bh, f0[mf]);
        f1[mf] = mfmah(qf1[kf], bh, f1[mf]);
      }
    }
    __builtin_amdgcn_s_setprio(0);

    // ---- online softmax + P write, per half ----
    #pragma unroll
    for (int h=0; h<2; ++h){
      f32x4* f = h ? f1 : f0;
      float* mr = h ? m1r : m0r;
      float* lr = h ? l1r : l0r;
      f32x4* oa = h ? oa1 : oa0;
      float pm[4], need = 0.f;
      #pragma unroll
      for (int j=0;j<4;++j){
        float mx = fmaxf(fmaxf(f[0][j], f[1][j]), fmaxf(f[2][j], f[3][j]));
        mx = fmaxf(mx, __shfl_xor(mx, 1));
        mx = fmaxf(mx, __shfl_xor(mx, 2));
        mx = fmaxf(mx, __shfl_xor(mx, 4));
        mx = fmaxf(mx, __shfl_xor(mx, 8));
        pm[j] = mx;
        need = fmaxf(need, mx - mr[j]);
      }
      if (__any(need > 8.f)){    // defer-max: rescale only on real max growth
        #pragma unroll
        for (int j=0;j<4;++j){
          float mn = fmaxf(mr[j], pm[j]);
          float al = __expf(mr[j] - mn);
          mr[j] = mn;
          lr[j] *= al;
          #pragma unroll
          for (int cf=0;cf<8;++cf) oa[cf][j] *= al;
        }
      }
      #pragma unroll
      for (int j=0;j<4;++j){
        float sm = 0.f;
        #pragma unroll
        for (int mf=0;mf<4;++mf){
          float pv = __expf(f[mf][j] - mr[j]);
          f[mf][j] = pv;
          sm += pv;
        }
        sm += __shfl_xor(sm, 1);
        sm += __shfl_xor(sm, 2);
        sm += __shfl_xor(sm, 4);
        sm += __shfl_xor(sm, 8);
        lr[j] += sm;
      }
      // P write (wave-private rows)
      #pragma unroll
      for (int mf=0;mf<4;++mf)
        #pragma unroll
        for (int j=0;j<4;++j){
          int r = h*64 + 16*w + (l>>4)*4 + j;
          int cc = 16*mf + (l&15);
          ps[r][swz(r,cc)] = f2h(f[mf][j]);
        }
    }

    // ---- PV, V fragments shared across halves ----
    __builtin_amdgcn_s_setprio(1);
    {
      int pr0 = 16*w + (l&15), pr1 = 64 + pr0;
      #pragma unroll
      for (int mk=0;mk<2;++mk){
        int ko = mk*32 + (l>>4)*8;
        short8 ap0 = *(const short8*)&ps[pr0][swz(pr0,ko)];
        short8 ap1 = *(const short8*)&ps[pr1][swz(pr1,ko)];
        #pragma unroll
        for (int cf=0;cf<8;++cf){
          int vr = 16*cf + (l&15);
          short8 bv = *(const short8*)&vb[cur][vr][swz(vr,ko)];
          oa0[cf] = mfmah(ap0, bv, oa0[cf]);
          oa1[cf] = mfmah(ap1, bv, oa1[cf]);
        }
      }
    }
    __builtin_amdgcn_s_setprio(0);

    __syncthreads();   // drains prefetch (covered by compute) + buffer handoff
    cur ^= 1;
  }

  // ---- epilogue: normalized partials + (m,l) ----
  #pragma unroll
  for (int h=0; h<2; ++h){
    float* mr = h ? m1r : m0r;
    float* lr = h ? l1r : l0r;
    f32x4* oa = h ? oa1 : oa0;
    #pragma unroll
    for (int j=0;j<4;++j){
      float inv = 1.f / lr[j];
      int n = n0 + h*64 + 16*w + (l>>4)*4 + j;
      #pragma unroll
      for (int cf=0;cf<8;++cf){
        int c = 16*cf + (l&15);
        ypart[(((size_t)s*4 + b)*NSP + n)*ICH + c] = f2h(oa[cf][j]*inv);
      }
      if ((l&15)==0){
        ml[(((size_t)s*4 + b)*NSP + n)*2 + 0] = mr[j];
        ml[(((size_t)s*4 + b)*NSP + n)*2 + 1] = lr[j];
      }
    }
  }
}

// ---------------------------------------------------------------------------
// Final conv + fused split-combine (unchanged from round 2)
// ---------------------------------------------------------------------------
__global__ __launch_bounds__(256) void final_k(
  const unsigned short* __restrict__ ypart, const float* __restrict__ ml,
  const float* __restrict__ x, const float* __restrict__ Wm,
  const float* __restrict__ bias, const float* __restrict__ gamma,
  const float* __restrict__ beta, const float* __restrict__ mean,
  const float* __restrict__ var, float* __restrict__ out)
{
  const int b = blockIdx.z, ot = blockIdx.y, nt = blockIdx.x;
  const int n0 = nt*64, o0 = ot*64;
  const int t = threadIdx.x, w = t>>6, l = t&63;
  __shared__ unsigned short ys[64][128];
  __shared__ unsigned short w2s[64][128];
  __shared__ float wc[SPLITS][64];
  __shared__ float sc_s[64], sh_s[64];
  if (t < 64){
    int o = o0 + t;
    float s = gamma[o]*rsqrtf(var[o]+1e-5f);
    sc_s[t]=s; sh_s[t]=beta[o]-mean[o]*s+bias[o]*s;
  } else if (t < 128){
    int r = t - 64, n = n0 + r;
    float mv[SPLITS], lv[SPLITS];
    #pragma unroll
    for (int s=0;s<SPLITS;++s){
      mv[s] = ml[(((size_t)s*4 + b)*NSP + n)*2 + 0];
      lv[s] = ml[(((size_t)s*4 + b)*NSP + n)*2 + 1];
    }
    float M = fmaxf(fmaxf(mv[0],mv[1]), fmaxf(mv[2],mv[3]));
    float wsum = 0.f, wv[SPLITS];
    #pragma unroll
    for (int s=0;s<SPLITS;++s){ wv[s] = lv[s]*__expf(mv[s]-M); wsum += wv[s]; }
    float inv = 1.f/wsum;
    #pragma unroll
    for (int s=0;s<SPLITS;++s) wc[s][r] = wv[s]*inv;
  }
  __syncthreads();
  #pragma unroll
  for (int p=0;p<4;++p){
    int id = p*256 + t, r = id>>4, c8 = (id&15)*8;
    float accv[8] = {0,0,0,0,0,0,0,0};
    #pragma unroll
    for (int s=0;s<SPLITS;++s){
      short8 v = *(const short8*)(ypart + (((size_t)s*4 + b)*NSP + n0 + r)*ICH + c8);
      float wgt = wc[s][r];
      #pragma unroll
      for (int i=0;i<8;++i) accv[i] += wgt * h2f(((unsigned short*)&v)[i]);
    }
    unsigned short hv[8];
    #pragma unroll
    for (int i=0;i<8;++i) hv[i] = f2h(accv[i]);
    *(short8*)&ys[r][swz(r,c8)] = *(short8*)hv;

    float4 u0 = *(const float4*)(Wm + (size_t)(o0 + r)*ICH + c8);
    float4 u1 = *(const float4*)(Wm + (size_t)(o0 + r)*ICH + c8 + 4);
    unsigned short wh[8] = {f2h(u0.x),f2h(u0.y),f2h(u0.z),f2h(u0.w),
                            f2h(u1.x),f2h(u1.y),f2h(u1.z),f2h(u1.w)};
    *(short8*)&w2s[r][swz(r,c8)] = *(short8*)wh;
  }
  __syncthreads();
  const f32x4 Z = {0.f,0.f,0.f,0.f};
  f32x4 acc[4];
  for (int i=0;i<4;++i) acc[i]=Z;
  #pragma unroll
  for (int kf=0;kf<4;++kf){
    int ko = kf*32 + (l>>4)*8;
    int wr = 16*w + (l&15);
    short8 a = *(const short8*)&w2s[wr][swz(wr,ko)];
    #pragma unroll
    for (int nf=0;nf<4;++nf){
      int yr = 16*nf + (l&15);
      short8 bb = *(const short8*)&ys[yr][swz(yr,ko)];
      acc[nf] = mfmah(a, bb, acc[nf]);
    }
  }
  #pragma unroll
  for (int j=0;j<4;++j){
    int ol = 16*w + (l>>4)*4 + j;
    float s = sc_s[ol], sh = sh_s[ol];
    #pragma unroll
    for (int nf=0;nf<4;++nf){
      int n = n0 + 16*nf + (l&15);
      size_t idx = ((size_t)b*CIN + o0 + ol)*NSP + n;
      out[idx] = acc[nf][j]*s + sh + x[idx];
    }
  }
}

extern "C" void kernel_launch(void* const* d_in, const int* in_sizes, int n_in,
                              void* d_out, int out_size, void* d_ws, size_t ws_size,
                              hipStream_t stream){
  const float* x    = (const float*)d_in[0];
  const float* g_w  = (const float*)d_in[1];
  const float* g_b  = (const float*)d_in[2];
  const float* g_ga = (const float*)d_in[3];
  const float* g_be = (const float*)d_in[4];
  const float* g_me = (const float*)d_in[5];
  const float* g_va = (const float*)d_in[6];
  const float* t_w  = (const float*)d_in[7];
  const float* t_b  = (const float*)d_in[8];
  const float* t_ga = (const float*)d_in[9];
  const float* t_be = (const float*)d_in[10];
  const float* t_me = (const float*)d_in[11];
  const float* t_va = (const float*)d_in[12];
  const float* p_w  = (const float*)d_in[13];
  const float* p_b  = (const float*)d_in[14];
  const float* p_ga = (const float*)d_in[15];
  const float* p_be = (const float*)d_in[16];
  const float* p_me = (const float*)d_in[17];
  const float* p_va = (const float*)d_in[18];
  const float* w_w  = (const float*)d_in[19];
  const float* w_b  = (const float*)d_in[20];
  const float* w_ga = (const float*)d_in[21];
  const float* w_be = (const float*)d_in[22];
  const float* w_me = (const float*)d_in[23];
  const float* w_va = (const float*)d_in[24];

  char* ws = (char*)d_ws;
  const size_t SEG = (size_t)4*NSP*ICH*sizeof(unsigned short);   // 4 MB
  unsigned short* th_t  = (unsigned short*)(ws);
  unsigned short* ph_t  = (unsigned short*)(ws + SEG);
  unsigned short* g_cn  = (unsigned short*)(ws + 2*SEG);
  unsigned short* ypart = (unsigned short*)(ws + 3*SEG);
  float*          mlb   = (float*)(ws + 3*SEG + SPLITS*SEG);

  dim3 blk(256,1,1);
  conv_fused_k<<<dim3(64,2,4), blk, 0, stream>>>(
      x,
      g_w, g_b, g_ga, g_be, g_me, g_va,
      t_w, t_b, t_ga, t_be, t_me, t_va,
      p_w, p_b, p_ga, p_be, p_me, p_va,
      g_cn, th_t, ph_t);
  attn_k<<<dim3(512,1,1), blk, 0, stream>>>(th_t, ph_t, g_cn, ypart, mlb);
  final_k<<<dim3(64,4,4), blk, 0, stream>>>(ypart, mlb, x, w_w, w_b, w_ga, w_be, w_me, w_va, (float*)d_out);
}

// Round 5
// 74.710 us; speedup vs baseline: 3.6050x; 1.2717x over previous
//
#include <hip/hip_runtime.h>
#include <math.h>

typedef __attribute__((ext_vector_type(8))) short short8;
typedef __attribute__((ext_vector_type(8))) _Float16 half8;
typedef __attribute__((ext_vector_type(4))) float f32x4;

#define NSP 4096
#define CIN 256
#define ICH 128
#define SPLITS 4
#define TILES_PER_SPLIT 16

__device__ __forceinline__ unsigned short f2h(float x){
  union { _Float16 h; unsigned short u; } v; v.h = (_Float16)x; return v.u;
}
__device__ __forceinline__ float h2f(unsigned short u){
  union { _Float16 h; unsigned short u; } v; v.u = u; return (float)v.h;
}
// pack two f32 -> two f16 in one u32 (v_cvt_pkrtz_f16_f32)
__device__ __forceinline__ unsigned pk2h(float a, float b){
  union { __fp16 __attribute__((ext_vector_type(2))) v; unsigned u; } r;
  r.v = __builtin_amdgcn_cvt_pkrtz(a, b);
  return r.u;
}
// LDS anti-bank-conflict swizzle (element units; 8-chunk preserving)
__device__ __forceinline__ int swz(int row, int e){ return e ^ ((row & 7) << 3); }

__device__ __forceinline__ f32x4 mfmah(short8 a, short8 b, f32x4 c){
  union { short8 s; half8 h; } ua, ub; ua.s = a; ub.s = b;
  return __builtin_amdgcn_mfma_f32_16x16x32_f16(ua.h, ub.h, c, 0, 0, 0);
}

__device__ __forceinline__ void st4h(unsigned short* p, unsigned short a, unsigned short b,
                                     unsigned short c, unsigned short d){
  ushort4 v; v.x=a; v.y=b; v.z=c; v.w=d;
  *(ushort4*)p = v;
}

// async global->LDS, 16B per lane. LDS dest = wave-uniform base + lane*16 (linear).
__device__ __forceinline__ void gload_lds16(const unsigned short* g, unsigned short* l){
  __builtin_amdgcn_global_load_lds(
      (const __attribute__((address_space(1))) unsigned int*)g,
      (__attribute__((address_space(3))) unsigned int*)l, 16, 0, 0);
}

// Stage a 64x128 fp16 tile (row stride 128 elems in global) into LDS flat [64][128]
// with read-side XOR swizzle pre-applied on the SOURCE address (rule 21).
__device__ __forceinline__ void stage_nc(const unsigned short* gbase, unsigned short* lds,
                                         int w, int l){
  #pragma unroll
  for (int i=0;i<4;++i){
    int rl = 16*w + 4*i + (l>>4);
    int eg = ((l&15)*8) ^ ((rl&7)<<3);
    gload_lds16(gbase + (size_t)rl*128 + eg, lds + w*2048 + i*512);
  }
}
// Stage a 128x64 fp16 tile (row stride NSP elems in global) into LDS flat [128][64].
__device__ __forceinline__ void stage_cn(const unsigned short* gbase, unsigned short* lds,
                                         int w, int l){
  #pragma unroll
  for (int i=0;i<4;++i){
    int cl = 32*w + 8*i + (l>>3);
    int me = ((l&7)*8) ^ ((cl&7)<<3);
    gload_lds16(gbase + (size_t)cl*NSP + me, lds + w*2048 + i*512);
  }
}

// ---------------------------------------------------------------------------
// Fused 3-branch conv+BN+ReLU: reads x once, computes g/theta/phi tiles.
// ---------------------------------------------------------------------------
__global__ __launch_bounds__(256) void conv_fused_k(
    const float* __restrict__ x,
    const float* __restrict__ w0, const float* __restrict__ b0,
    const float* __restrict__ ga0, const float* __restrict__ be0,
    const float* __restrict__ me0, const float* __restrict__ va0,
    const float* __restrict__ w1, const float* __restrict__ b1,
    const float* __restrict__ ga1, const float* __restrict__ be1,
    const float* __restrict__ me1, const float* __restrict__ va1,
    const float* __restrict__ w2, const float* __restrict__ b2,
    const float* __restrict__ ga2, const float* __restrict__ be2,
    const float* __restrict__ me2, const float* __restrict__ va2,
    unsigned short* __restrict__ outg, unsigned short* __restrict__ outt,
    unsigned short* __restrict__ outp)
{
  const int b = blockIdx.z, nt = blockIdx.x, ot = blockIdx.y;
  const int n0 = nt*64, o0 = ot*64;
  const int t = threadIdx.x, w = t>>6, l = t&63;
  __shared__ unsigned short xs[64][64];       // [n][c] fp16
  __shared__ unsigned short ws[3][64][64];    // [br][o][c] fp16
  __shared__ float sc_s[3][64], sh_s[3][64];
  if (t < 64){
    int o = o0 + t;
    float s0 = ga0[o]*rsqrtf(va0[o]+1e-5f);
    sc_s[0][t]=s0; sh_s[0][t]=be0[o]-me0[o]*s0+b0[o]*s0;
    float s1 = ga1[o]*rsqrtf(va1[o]+1e-5f);
    sc_s[1][t]=s1; sh_s[1][t]=be1[o]-me1[o]*s1+b1[o]*s1;
    float s2 = ga2[o]*rsqrtf(va2[o]+1e-5f);
    sc_s[2][t]=s2; sh_s[2][t]=be2[o]-me2[o]*s2+b2[o]*s2;
  }
  const f32x4 Z = {0.f,0.f,0.f,0.f};
  f32x4 acc[3][4];
  #pragma unroll
  for (int br=0;br<3;++br) for (int i=0;i<4;++i) acc[br][i] = Z;
  const float* Wt[3] = {w0, w1, w2};

  for (int kc = 0; kc < CIN; kc += 64){
    __syncthreads();
    #pragma unroll
    for (int p = 0; p < 4; ++p){
      int cw = p*16 + (t>>4);
      int q4 = (t&15)*4;
      float4 xv = *(const float4*)(x + ((size_t)b*CIN + kc + cw)*NSP + n0 + q4);
      float xa[4] = {xv.x, xv.y, xv.z, xv.w};
      #pragma unroll
      for (int i=0;i<4;++i){
        int r = q4 + i;
        xs[r][swz(r, cw)] = f2h(xa[i]);
      }
      #pragma unroll
      for (int br=0;br<3;++br){
        float4 wv = *(const float4*)(Wt[br] + (size_t)(o0 + cw)*CIN + kc + q4);
        int cs = swz(cw, q4);
        st4h(&ws[br][cw][cs], f2h(wv.x), f2h(wv.y), f2h(wv.z), f2h(wv.w));
      }
    }
    __syncthreads();
    #pragma unroll
    for (int kf = 0; kf < 2; ++kf){
      int ko = kf*32 + (l>>4)*8;
      int wr = 16*w + (l&15);
      short8 wf0 = *(const short8*)&ws[0][wr][swz(wr, ko)];
      short8 wf1 = *(const short8*)&ws[1][wr][swz(wr, ko)];
      short8 wf2 = *(const short8*)&ws[2][wr][swz(wr, ko)];
      #pragma unroll
      for (int nf = 0; nf < 4; ++nf){
        int xr = 16*nf + (l&15);
        short8 xf = *(const short8*)&xs[xr][swz(xr, ko)];
        acc[0][nf] = mfmah(wf0, xf, acc[0][nf]);   // orient0 (g)
        acc[1][nf] = mfmah(xf, wf1, acc[1][nf]);   // orient1 (theta)
        acc[2][nf] = mfmah(xf, wf2, acc[2][nf]);   // orient1 (phi)
      }
    }
  }
  #pragma unroll
  for (int j=0;j<4;++j){
    int ol = 16*w + (l>>4)*4 + j;
    float s = sc_s[0][ol], sh = sh_s[0][ol];
    #pragma unroll
    for (int nf=0;nf<4;++nf){
      int n = n0 + 16*nf + (l&15);
      float v = fmaxf(acc[0][nf][j]*s + sh, 0.f);
      outg[((size_t)b*ICH + o0 + ol)*NSP + n] = f2h(v);
    }
  }
  {
    int ol = 16*w + (l&15);
    float s1 = sc_s[1][ol], sh1 = sh_s[1][ol];
    float s2 = sc_s[2][ol], sh2 = sh_s[2][ol];
    #pragma unroll
    for (int nf=0; nf<4; ++nf)
      #pragma unroll
      for (int j=0;j<4;++j){
        int n = n0 + 16*nf + (l>>4)*4 + j;
        float v1 = fmaxf(acc[1][nf][j]*s1 + sh1, 0.f);
        float v2 = fmaxf(acc[2][nf][j]*s2 + sh2, 0.f);
        outt[((size_t)b*NSP + n)*ICH + o0 + ol] = f2h(v1);
        outp[((size_t)b*NSP + n)*ICH + o0 + ol] = f2h(v2);
      }
  }
}

// ---------------------------------------------------------------------------
// Flash attention, Q=128 rows/block, swapped QK^T (P column lane-local ->
// in-register softmax reductions, 2 shuffles per half), double-buffered K/V
// via global_load_lds, 2-phase pipeline, KV-split over 4 splits.
// ---------------------------------------------------------------------------
__global__ __launch_bounds__(256, 2) void attn_k(
  const unsigned short* __restrict__ thp, const unsigned short* __restrict__ php,
  const unsigned short* __restrict__ gb, unsigned short* __restrict__ ypart,
  float* __restrict__ ml)
{
  // bijective XCD-aware decode: each XCD gets 2 (b,s) combos x 32 qt blocks
  const int bx = blockIdx.x;
  const int xcd = bx & 7, jj = bx >> 3;
  const int combo = xcd*2 + (jj>>5);
  const int qt = jj & 31;
  const int b = combo & 3, s = combo >> 2;
  const int n0 = qt*128;
  const int t = threadIdx.x, w = t>>6, l = t&63;

  __shared__ unsigned short kb[2][64][128];   // K double buffer
  __shared__ unsigned short vb[2][128][64];   // V double buffer ([c][m])
  __shared__ unsigned short ps[128][64];      // P tile [n][m]

  // ---- stage Q (both halves) through kb, pull fragments ----
  stage_nc(thp + ((size_t)b*NSP + n0      )*ICH, &kb[0][0][0], w, l);
  stage_nc(thp + ((size_t)b*NSP + n0 + 64 )*ICH, &kb[1][0][0], w, l);
  __syncthreads();
  short8 qf0[4], qf1[4];
  {
    int qr = 16*w + (l&15);
    #pragma unroll
    for (int kf=0;kf<4;++kf){
      int ko = kf*32 + (l>>4)*8;
      qf0[kf] = *(const short8*)&kb[0][qr][swz(qr, ko)];
      qf1[kf] = *(const short8*)&kb[1][qr][swz(qr, ko)];
    }
  }
  __syncthreads();   // all waves done reading Q before restage

  const f32x4 Z = {0.f,0.f,0.f,0.f};
  f32x4 oa0[8], oa1[8];
  #pragma unroll
  for (int i=0;i<8;++i){ oa0[i]=Z; oa1[i]=Z; }
  // per-lane scalars: this lane owns softmax state for Q row n = h*64+16w+(l&15)
  float m0r = -1e30f, m1r = -1e30f;
  float l0r = 0.f, l1r = 0.f;

  const int tile0 = s*TILES_PER_SPLIT;
  stage_nc(php + ((size_t)b*NSP + tile0*64)*ICH, &kb[0][0][0], w, l);
  stage_cn(gb + (size_t)b*ICH*NSP + tile0*64,    &vb[0][0][0], w, l);
  __syncthreads();
  int cur = 0;

  for (int it = 0; it < TILES_PER_SPLIT; ++it){
    if (it < TILES_PER_SPLIT-1){
      int m0n = (tile0 + it + 1)*64;
      stage_nc(php + ((size_t)b*NSP + m0n)*ICH, &kb[cur^1][0][0], w, l);
      stage_cn(gb + (size_t)b*ICH*NSP + m0n,    &vb[cur^1][0][0], w, l);
    }
    // ---- swapped QK^T: f[mf] rows = m (KV), cols = n (Q). K frags shared ----
    f32x4 f0[4], f1[4];
    #pragma unroll
    for (int i=0;i<4;++i){ f0[i]=Z; f1[i]=Z; }
    __builtin_amdgcn_s_setprio(1);
    #pragma unroll
    for (int mf=0; mf<4; ++mf){
      int kr = 16*mf + (l&15);
      #pragma unroll
      for (int kf=0; kf<4; ++kf){
        short8 bh = *(const short8*)&kb[cur][kr][swz(kr, kf*32 + (l>>4)*8)];
        f0[mf] = mfmah(bh, qf0[kf], f0[mf]);
        f1[mf] = mfmah(bh, qf1[kf], f1[mf]);
      }
    }
    __builtin_amdgcn_s_setprio(0);

    // ---- online softmax, P column lane-local: reduce in-register + 2 shfl ----
    #pragma unroll
    for (int h=0; h<2; ++h){
      f32x4* f = h ? f1 : f0;
      float& mr = h ? m1r : m0r;
      float& lr = h ? l1r : l0r;
      f32x4* oa = h ? oa1 : oa0;
      float mx = f[0][0];
      #pragma unroll
      for (int mf=0;mf<4;++mf)
        #pragma unroll
        for (int j=0;j<4;++j) mx = fmaxf(mx, f[mf][j]);
      mx = fmaxf(mx, __shfl_xor(mx, 16));
      mx = fmaxf(mx, __shfl_xor(mx, 32));
      if (__any(mx - mr > 8.f)){    // defer-max: rescale only on real max growth
        float mn = fmaxf(mr, mx);
        float al = __expf(mr - mn);
        mr = mn; lr *= al;
        #pragma unroll
        for (int j=0;j<4;++j){
          float alj = __shfl(al, (l>>4)*4 + j);   // alpha of oa row (l>>4)*4+j
          #pragma unroll
          for (int cf=0;cf<8;++cf) oa[cf][j] *= alj;
        }
      }
      float sm = 0.f;
      #pragma unroll
      for (int mf=0;mf<4;++mf)
        #pragma unroll
        for (int j=0;j<4;++j){
          float pv = __expf(f[mf][j] - mr);
          f[mf][j] = pv;
          sm += pv;
        }
      sm += __shfl_xor(sm, 16);
      sm += __shfl_xor(sm, 32);
      lr += sm;
      // P write: lane owns column n, rows m = 16mf+4(l>>4)+j; pack pairs -> b32
      int r = h*64 + 16*w + (l&15);
      int cb = 4*(l>>4);
      #pragma unroll
      for (int mf=0;mf<4;++mf)
        #pragma unroll
        for (int p=0;p<2;++p){
          unsigned pk = pk2h(f[mf][2*p], f[mf][2*p+1]);
          int cc = 16*mf + cb + 2*p;
          *(unsigned*)&ps[r][swz(r,cc)] = pk;
        }
    }

    // ---- PV, V fragments shared across halves ----
    __builtin_amdgcn_s_setprio(1);
    {
      int pr0 = 16*w + (l&15), pr1 = 64 + pr0;
      #pragma unroll
      for (int mk=0;mk<2;++mk){
        int ko = mk*32 + (l>>4)*8;
        short8 ap0 = *(const short8*)&ps[pr0][swz(pr0,ko)];
        short8 ap1 = *(const short8*)&ps[pr1][swz(pr1,ko)];
        #pragma unroll
        for (int cf=0;cf<8;++cf){
          int vr = 16*cf + (l&15);
          short8 bv = *(const short8*)&vb[cur][vr][swz(vr,ko)];
          oa0[cf] = mfmah(ap0, bv, oa0[cf]);
          oa1[cf] = mfmah(ap1, bv, oa1[cf]);
        }
      }
    }
    __builtin_amdgcn_s_setprio(0);

    __syncthreads();   // drains prefetch (covered by compute) + buffer handoff
    cur ^= 1;
  }

  // ---- epilogue: normalized partials + (m,l) ----
  #pragma unroll
  for (int h=0; h<2; ++h){
    float mr = h ? m1r : m0r;
    float lr = h ? l1r : l0r;
    f32x4* oa = h ? oa1 : oa0;
    float invl = 1.f / lr;
    #pragma unroll
    for (int j=0;j<4;++j){
      float inv = __shfl(invl, (l>>4)*4 + j);
      int n = n0 + h*64 + 16*w + (l>>4)*4 + j;
      #pragma unroll
      for (int cf=0;cf<8;++cf){
        int c = 16*cf + (l&15);
        ypart[(((size_t)s*4 + b)*NSP + n)*ICH + c] = f2h(oa[cf][j]*inv);
      }
    }
    if (l < 16){
      int n = n0 + h*64 + 16*w + l;
      ml[(((size_t)s*4 + b)*NSP + n)*2 + 0] = mr;
      ml[(((size_t)s*4 + b)*NSP + n)*2 + 1] = lr;
    }
  }
}

// ---------------------------------------------------------------------------
// Final conv + fused split-combine
// ---------------------------------------------------------------------------
__global__ __launch_bounds__(256) void final_k(
  const unsigned short* __restrict__ ypart, const float* __restrict__ ml,
  const float* __restrict__ x, const float* __restrict__ Wm,
  const float* __restrict__ bias, const float* __restrict__ gamma,
  const float* __restrict__ beta, const float* __restrict__ mean,
  const float* __restrict__ var, float* __restrict__ out)
{
  const int b = blockIdx.z, ot = blockIdx.y, nt = blockIdx.x;
  const int n0 = nt*64, o0 = ot*64;
  const int t = threadIdx.x, w = t>>6, l = t&63;
  __shared__ unsigned short ys[64][128];
  __shared__ unsigned short w2s[64][128];
  __shared__ float wc[SPLITS][64];
  __shared__ float sc_s[64], sh_s[64];
  if (t < 64){
    int o = o0 + t;
    float s = gamma[o]*rsqrtf(var[o]+1e-5f);
    sc_s[t]=s; sh_s[t]=beta[o]-mean[o]*s+bias[o]*s;
  } else if (t < 128){
    int r = t - 64, n = n0 + r;
    float mv[SPLITS], lv[SPLITS];
    #pragma unroll
    for (int s=0;s<SPLITS;++s){
      mv[s] = ml[(((size_t)s*4 + b)*NSP + n)*2 + 0];
      lv[s] = ml[(((size_t)s*4 + b)*NSP + n)*2 + 1];
    }
    float M = fmaxf(fmaxf(mv[0],mv[1]), fmaxf(mv[2],mv[3]));
    float wsum = 0.f, wv[SPLITS];
    #pragma unroll
    for (int s=0;s<SPLITS;++s){ wv[s] = lv[s]*__expf(mv[s]-M); wsum += wv[s]; }
    float inv = 1.f/wsum;
    #pragma unroll
    for (int s=0;s<SPLITS;++s) wc[s][r] = wv[s]*inv;
  }
  __syncthreads();
  #pragma unroll
  for (int p=0;p<4;++p){
    int id = p*256 + t, r = id>>4, c8 = (id&15)*8;
    float accv[8] = {0,0,0,0,0,0,0,0};
    #pragma unroll
    for (int s=0;s<SPLITS;++s){
      short8 v = *(const short8*)(ypart + (((size_t)s*4 + b)*NSP + n0 + r)*ICH + c8);
      float wgt = wc[s][r];
      #pragma unroll
      for (int i=0;i<8;++i) accv[i] += wgt * h2f(((unsigned short*)&v)[i]);
    }
    unsigned short hv[8];
    #pragma unroll
    for (int i=0;i<8;++i) hv[i] = f2h(accv[i]);
    *(short8*)&ys[r][swz(r,c8)] = *(short8*)hv;

    float4 u0 = *(const float4*)(Wm + (size_t)(o0 + r)*ICH + c8);
    float4 u1 = *(const float4*)(Wm + (size_t)(o0 + r)*ICH + c8 + 4);
    unsigned short wh[8] = {f2h(u0.x),f2h(u0.y),f2h(u0.z),f2h(u0.w),
                            f2h(u1.x),f2h(u1.y),f2h(u1.z),f2h(u1.w)};
    *(short8*)&w2s[r][swz(r,c8)] = *(short8*)wh;
  }
  __syncthreads();
  const f32x4 Z = {0.f,0.f,0.f,0.f};
  f32x4 acc[4];
  for (int i=0;i<4;++i) acc[i]=Z;
  #pragma unroll
  for (int kf=0;kf<4;++kf){
    int ko = kf*32 + (l>>4)*8;
    int wr = 16*w + (l&15);
    short8 a = *(const short8*)&w2s[wr][swz(wr,ko)];
    #pragma unroll
    for (int nf=0;nf<4;++nf){
      int yr = 16*nf + (l&15);
      short8 bb = *(const short8*)&ys[yr][swz(yr,ko)];
      acc[nf] = mfmah(a, bb, acc[nf]);
    }
  }
  #pragma unroll
  for (int j=0;j<4;++j){
    int ol = 16*w + (l>>4)*4 + j;
    float s = sc_s[ol], sh = sh_s[ol];
    #pragma unroll
    for (int nf=0;nf<4;++nf){
      int n = n0 + 16*nf + (l&15);
      size_t idx = ((size_t)b*CIN + o0 + ol)*NSP + n;
      out[idx] = acc[nf][j]*s + sh + x[idx];
    }
  }
}

extern "C" void kernel_launch(void* const* d_in, const int* in_sizes, int n_in,
                              void* d_out, int out_size, void* d_ws, size_t ws_size,
                              hipStream_t stream){
  const float* x    = (const float*)d_in[0];
  const float* g_w  = (const float*)d_in[1];
  const float* g_b  = (const float*)d_in[2];
  const float* g_ga = (const float*)d_in[3];
  const float* g_be = (const float*)d_in[4];
  const float* g_me = (const float*)d_in[5];
  const float* g_va = (const float*)d_in[6];
  const float* t_w  = (const float*)d_in[7];
  const float* t_b  = (const float*)d_in[8];
  const float* t_ga = (const float*)d_in[9];
  const float* t_be = (const float*)d_in[10];
  const float* t_me = (const float*)d_in[11];
  const float* t_va = (const float*)d_in[12];
  const float* p_w  = (const float*)d_in[13];
  const float* p_b  = (const float*)d_in[14];
  const float* p_ga = (const float*)d_in[15];
  const float* p_be = (const float*)d_in[16];
  const float* p_me = (const float*)d_in[17];
  const float* p_va = (const float*)d_in[18];
  const float* w_w  = (const float*)d_in[19];
  const float* w_b  = (const float*)d_in[20];
  const float* w_ga = (const float*)d_in[21];
  const float* w_be = (const float*)d_in[22];
  const float* w_me = (const float*)d_in[23];
  const float* w_va = (const float*)d_in[24];

  char* ws = (char*)d_ws;
  const size_t SEG = (size_t)4*NSP*ICH*sizeof(unsigned short);   // 4 MB
  unsigned short* th_t  = (unsigned short*)(ws);
  unsigned short* ph_t  = (unsigned short*)(ws + SEG);
  unsigned short* g_cn  = (unsigned short*)(ws + 2*SEG);
  unsigned short* ypart = (unsigned short*)(ws + 3*SEG);
  float*          mlb   = (float*)(ws + 3*SEG + SPLITS*SEG);

  dim3 blk(256,1,1);
  conv_fused_k<<<dim3(64,2,4), blk, 0, stream>>>(
      x,
      g_w, g_b, g_ga, g_be, g_me, g_va,
      t_w, t_b, t_ga, t_be, t_me, t_va,
      p_w, p_b, p_ga, p_be, p_me, p_va,
      g_cn, th_t, ph_t);
  attn_k<<<dim3(512,1,1), blk, 0, stream>>>(th_t, ph_t, g_cn, ypart, mlb);
  final_k<<<dim3(64,4,4), blk, 0, stream>>>(ypart, mlb, x, w_w, w_b, w_ga, w_be, w_me, w_va, (float*)d_out);
}